// Round 6
// baseline (423.172 us; speedup 1.0000x reference)
//
#include <hip/hip_runtime.h>
#include <hip/hip_bf16.h>
#include <cstdint>

// ---------------- static problem config ----------------
#define D_MODEL   256
#define N_HEADS   8
#define N_LEVELS  4
#define N_POINTS  4
#define D_FFN     1024
#define D_HEAD    32
#define LEN_IN    13294          // 100*100 + 50*50 + 25*25 + 13*13
#define NBATCH    2
#define M_TOK     (NBATCH * LEN_IN)   // 26588
#define M_PAD     26624               // 208 * 128 = 416 * 64

__constant__ int c_lvl_h[4] = {100, 50, 25, 13};
__constant__ int c_lvl_w[4] = {100, 50, 25, 13};
__constant__ int c_lvl_s[4] = {0, 10000, 12500, 13125};

typedef __attribute__((ext_vector_type(8))) __bf16 bf16x8;
typedef __attribute__((ext_vector_type(4))) __bf16 bf16x4;
typedef __attribute__((ext_vector_type(4))) float  f32x4;
typedef __attribute__((ext_vector_type(4))) uint32_t u32x4;

__device__ __forceinline__ float bflo(uint32_t w) { return __uint_as_float(w << 16); }
__device__ __forceinline__ float bfhi(uint32_t w) { return __uint_as_float(w & 0xffff0000u); }

// ---------------- prep: weight transposes + bias concat + src/q cvt, ONE dispatch ----------------
__global__ __launch_bounds__(256) void prep(
    const float* __restrict__ s0, const float* __restrict__ s1, const float* __restrict__ s2,
    const float* __restrict__ s3, const float* __restrict__ s4, const float* __restrict__ s5,
    __bf16* __restrict__ d0, __bf16* __restrict__ d1, __bf16* __restrict__ d2,
    __bf16* __restrict__ d3, __bf16* __restrict__ d4, __bf16* __restrict__ d5,
    const float* __restrict__ b_off, const float* __restrict__ b_attn,
    float* __restrict__ bias_oa,
    const float4* __restrict__ src, const float4* __restrict__ pos,
    bf16x4* __restrict__ sb, bf16x4* __restrict__ qb, int n4)
{
    const int tid = threadIdx.x;
    const int b = blockIdx.x;
    if (b >= 737) {   // cvt path
        const int i = (b - 737) * 256 + tid;
        if (i >= n4) return;
        const float4 s = src[i];
        const float4 p = pos[i];
        bf16x4 sv = { (__bf16)s.x, (__bf16)s.y, (__bf16)s.z, (__bf16)s.w };
        bf16x4 qv = { (__bf16)(s.x + p.x), (__bf16)(s.y + p.y),
                      (__bf16)(s.z + p.z), (__bf16)(s.w + p.w) };
        sb[i] = sv;
        qb[i] = qv;
        return;
    }
    if (b == 736) {   // bias concat: [b_off(256) | b_attn(128)]
        if (tid < 256) bias_oa[tid] = b_off[tid];
        if (tid < 128) bias_oa[256 + tid] = b_attn[tid];
        return;
    }
    const int tx = tid & 31;
    const int ty = tid >> 5;
    const int starts[7] = {0, 64, 128, 160, 224, 480, 736};
    const int Ks[6] = {256, 256, 256, 256, 256, 1024};
    const int Ns[6] = {256, 256, 128, 256, 1024, 256};
    const float* srcs[6] = {s0, s1, s2, s3, s4, s5};
    __bf16* dsts[6] = {d0, d1, d2, d3, d4, d5};
    int i = 0;
    while (b >= starts[i + 1]) ++i;
    const int t = b - starts[i];
    const int K = Ks[i], N = Ns[i];
    const float* W = srcs[i];
    __bf16* Wt = dsts[i];
    const int ntx = N >> 5;
    const int n0 = (t % ntx) * 32;
    const int k0 = (t / ntx) * 32;

    __shared__ float tl[32][33];
    #pragma unroll
    for (int j = 0; j < 4; ++j)
        tl[ty + j * 8][tx] = W[(size_t)(k0 + ty + j * 8) * N + n0 + tx];
    __syncthreads();
    #pragma unroll
    for (int j = 0; j < 4; ++j)
        Wt[(size_t)(n0 + ty + j * 8) * K + k0 + tx] = (__bf16)tl[tx][ty + j * 8];
}

// ---------------- register-direct MFMA GEMM tile (no LDS, no barriers) ----------------
// One wave computes a 64x64 tile of C = A @ Bt^T. A [*,K] bf16 row-major, Bt [N,K].
// K-loop: 32-wide panels, register double-buffer (prefetch p+1 during MFMA of p).
template <bool RELU, int K, typename OutT>
__device__ __forceinline__ void gemm_rd_tile(
    const __bf16* __restrict__ A, const __bf16* __restrict__ Bt,
    const float* __restrict__ bias, OutT* __restrict__ C,
    int M, int N, int tm, int tn)
{
    const int lane = threadIdx.x & 63;
    const int fm  = lane & 15;          // fragment row (A) / col (B)
    const int fko = (lane >> 4) * 8;    // fragment k offset
    const __bf16* Ap = A  + (size_t)(tm * 64 + fm) * K + fko;
    const __bf16* Bp = Bt + (size_t)(tn * 64 + fm) * K + fko;

    f32x4 acc[4][4] = {};
    bf16x8 af[2][4], bfv[2][4];
    #pragma unroll
    for (int t = 0; t < 4; ++t) {
        af[0][t]  = *(const bf16x8*)(Ap + (size_t)(t * 16) * K);
        bfv[0][t] = *(const bf16x8*)(Bp + (size_t)(t * 16) * K);
    }
    constexpr int NPAN = K / 32;
    #pragma unroll
    for (int p = 0; p < NPAN; ++p) {
        const int cur = p & 1;
        const int nxt = cur ^ 1;
        if (p + 1 < NPAN) {
            const int ko = (p + 1) * 32;
            #pragma unroll
            for (int t = 0; t < 4; ++t) {
                af[nxt][t]  = *(const bf16x8*)(Ap + (size_t)(t * 16) * K + ko);
                bfv[nxt][t] = *(const bf16x8*)(Bp + (size_t)(t * 16) * K + ko);
            }
        }
        #pragma unroll
        for (int mt = 0; mt < 4; ++mt)
            #pragma unroll
            for (int nt = 0; nt < 4; ++nt)
                acc[mt][nt] = __builtin_amdgcn_mfma_f32_16x16x32_bf16(
                    af[cur][mt], bfv[cur][nt], acc[mt][nt], 0, 0, 0);
    }

    // C/D layout: col = lane&15, row = (lane>>4)*4 + reg  [m89-verified]
    const int ecol = lane & 15;
    const int erow = (lane >> 4) * 4;
    #pragma unroll
    for (int nt = 0; nt < 4; ++nt) {
        const int col = tn * 64 + nt * 16 + ecol;
        const float bv = bias[col];
        #pragma unroll
        for (int mt = 0; mt < 4; ++mt) {
            #pragma unroll
            for (int r = 0; r < 4; ++r) {
                const int row = tm * 64 + mt * 16 + erow + r;
                if (row < M) {
                    float v = acc[mt][nt][r] + bv;
                    if (RELU) v = fmaxf(v, 0.f);
                    C[(size_t)row * N + col] = (OutT)v;
                }
            }
        }
    }
}

// front GEMM: wave-tiles for value (416x4) then oa (416x6). grid 1040 blocks.
__global__ __launch_bounds__(256) void gemm_front_rd(
    const __bf16* __restrict__ A0, const __bf16* __restrict__ B0,
    const float* __restrict__ bi0, __bf16* __restrict__ C0,
    const __bf16* __restrict__ A1, const __bf16* __restrict__ B1,
    const float* __restrict__ bi1, __bf16* __restrict__ C1, int M)
{
    const int w = blockIdx.x * 4 + (threadIdx.x >> 6);
    if (w < 1664) {
        gemm_rd_tile<false, 256, __bf16>(A0, B0, bi0, C0, M, 256, w >> 2, w & 3);
    } else {
        const int t = w - 1664;
        gemm_rd_tile<false, 256, __bf16>(A1, B1, bi1, C1, M, 384, t / 6, t % 6);
    }
}

// FFN1: relu(x_b @ W1 + b1), N=1024. wave-tiles 416x16. grid 1664 blocks.
__global__ __launch_bounds__(256) void gemm_ffn1_rd(
    const __bf16* __restrict__ A, const __bf16* __restrict__ Bt,
    const float* __restrict__ bias, __bf16* __restrict__ C, int M)
{
    const int w = blockIdx.x * 4 + (threadIdx.x >> 6);
    gemm_rd_tile<true, 256, __bf16>(A, Bt, bias, C, M, 1024, w >> 4, w & 15);
}

// ---------------- reg-direct GEMM + residual + LayerNorm fused ----------------
// block: 64 rows x 256 cols (wave wv -> cols wv*64). 2 barriers total (LN combine).
template <typename OutT, int K>
__global__ __launch_bounds__(256) void gemm_ln_rd(
    const __bf16* __restrict__ A, const __bf16* __restrict__ Bt,
    const float* __restrict__ bias, const __bf16* __restrict__ res,
    const float* __restrict__ gamma, const float* __restrict__ beta,
    OutT* __restrict__ Cout, int M)
{
    __shared__ float lnsum[64][4];
    __shared__ float lnsq[64][4];
    __shared__ float lnstat[64][2];

    const int tid  = threadIdx.x;
    const int lane = tid & 63;
    const int wv   = tid >> 6;
    const int bm   = blockIdx.x * 64;
    const int wn   = wv * 64;
    const int fm   = lane & 15;
    const int fko  = (lane >> 4) * 8;
    const __bf16* Ap = A  + (size_t)(bm + fm) * K + fko;
    const __bf16* Bp = Bt + (size_t)(wn + fm) * K + fko;

    f32x4 acc[4][4] = {};
    bf16x8 af[2][4], bfv[2][4];
    #pragma unroll
    for (int t = 0; t < 4; ++t) {
        af[0][t]  = *(const bf16x8*)(Ap + (size_t)(t * 16) * K);
        bfv[0][t] = *(const bf16x8*)(Bp + (size_t)(t * 16) * K);
    }
    constexpr int NPAN = K / 32;
    #pragma unroll
    for (int p = 0; p < NPAN; ++p) {
        const int cur = p & 1;
        const int nxt = cur ^ 1;
        if (p + 1 < NPAN) {
            const int ko = (p + 1) * 32;
            #pragma unroll
            for (int t = 0; t < 4; ++t) {
                af[nxt][t]  = *(const bf16x8*)(Ap + (size_t)(t * 16) * K + ko);
                bfv[nxt][t] = *(const bf16x8*)(Bp + (size_t)(t * 16) * K + ko);
            }
        }
        #pragma unroll
        for (int mt = 0; mt < 4; ++mt)
            #pragma unroll
            for (int nt = 0; nt < 4; ++nt)
                acc[mt][nt] = __builtin_amdgcn_mfma_f32_16x16x32_bf16(
                    af[cur][mt], bfv[cur][nt], acc[mt][nt], 0, 0, 0);
    }

    const int ecol = lane & 15;
    const int erow = (lane >> 4) * 4;

    // bias + residual (in place)
    float g4[4], b4[4];
    #pragma unroll
    for (int nt = 0; nt < 4; ++nt) {
        const int col = wn + nt * 16 + ecol;
        g4[nt] = gamma[col];
        b4[nt] = beta[col];
        const float bv = bias[col];
        #pragma unroll
        for (int mt = 0; mt < 4; ++mt) {
            #pragma unroll
            for (int r = 0; r < 4; ++r) {
                const int row = bm + mt * 16 + erow + r;
                acc[mt][nt][r] += bv + (float)res[(size_t)row * 256 + col];
            }
        }
    }

    // per-row sums: partial over nt, shfl over the 16-lane quarter, LDS cross-wave
    #pragma unroll
    for (int mt = 0; mt < 4; ++mt) {
        #pragma unroll
        for (int r = 0; r < 4; ++r) {
            float s  = acc[mt][0][r] + acc[mt][1][r] + acc[mt][2][r] + acc[mt][3][r];
            float s2 = acc[mt][0][r] * acc[mt][0][r] + acc[mt][1][r] * acc[mt][1][r]
                     + acc[mt][2][r] * acc[mt][2][r] + acc[mt][3][r] * acc[mt][3][r];
            #pragma unroll
            for (int o = 1; o < 16; o <<= 1) {
                s  += __shfl_xor(s, o);
                s2 += __shfl_xor(s2, o);
            }
            if (ecol == 0) {
                const int rl = mt * 16 + erow + r;
                lnsum[rl][wv] = s;
                lnsq[rl][wv]  = s2;
            }
        }
    }
    __syncthreads();
    if (tid < 64) {
        const float s  = lnsum[tid][0] + lnsum[tid][1] + lnsum[tid][2] + lnsum[tid][3];
        const float s2 = lnsq[tid][0] + lnsq[tid][1] + lnsq[tid][2] + lnsq[tid][3];
        const float mu = s * (1.f / 256.f);
        const float var = s2 * (1.f / 256.f) - mu * mu;
        lnstat[tid][0] = mu;
        lnstat[tid][1] = rsqrtf(var + 1e-5f);
    }
    __syncthreads();

    #pragma unroll
    for (int mt = 0; mt < 4; ++mt) {
        #pragma unroll
        for (int r = 0; r < 4; ++r) {
            const int rl = mt * 16 + erow + r;
            const int row = bm + rl;
            const float mu = lnstat[rl][0];
            const float rs = lnstat[rl][1];
            if (row < M) {
                #pragma unroll
                for (int nt = 0; nt < 4; ++nt) {
                    const int col = wn + nt * 16 + ecol;
                    const float o = (acc[mt][nt][r] - mu) * rs * g4[nt] + b4[nt];
                    Cout[(size_t)row * 256 + col] = (OutT)o;
                }
            }
        }
    }
}

// ---------------- deformable sampling ----------------
// One token per block, 256 thr = 8 heads x 32 channels. Corner idx pre-scaled to BYTES.
__global__ __launch_bounds__(256) void msda_sample(
    const __bf16* __restrict__ value, // [Mpad, 256] bf16
    const __bf16* __restrict__ oa,    // [Mpad, 384] bf16: [off(256) | attn(128)]
    const float* __restrict__ refp,   // [M, 4, 2]
    __bf16* __restrict__ out)         // [Mpad, 256] bf16
{
    __shared__ uint32_t sc[8][16][8]; // per (h,lp): {i0,w0,i1,w1,i2,w2,i3,w3} ; 4 KB
    __shared__ float sw[8][16];       // softmax weights

    const int row = blockIdx.x;
    const int tid = threadIdx.x;

    uint32_t cidx[4];
    float    cwt[4];
    const int h  = tid >> 4;
    const int lp = tid & 15;

    if (tid < 128) {
        const int l  = lp >> 2;
        const int Ww = c_lvl_w[l];
        const int Hh = c_lvl_h[l];
        const uint32_t opk = *(const uint32_t*)(oa + (size_t)row * 384 + h * 32 + lp * 2);
        const float ox = bflo(opk), oy = bfhi(opk);
        const float rx = refp[((size_t)row * 4 + l) * 2 + 0];
        const float ry = refp[((size_t)row * 4 + l) * 2 + 1];
        const float x = (rx + ox / (float)Ww) * (float)Ww - 0.5f;
        const float y = (ry + oy / (float)Hh) * (float)Hh - 0.5f;
        const float xf = floorf(x), yf = floorf(y);
        const float fx = x - xf,    fy = y - yf;
        const int x0 = (int)xf, y0 = (int)yf;
        const int n  = row / LEN_IN;
        const int base = n * LEN_IN + c_lvl_s[l];
        #pragma unroll
        for (int c = 0; c < 4; ++c) {
            const int dx = c & 1, dy = c >> 1;
            const int xi = x0 + dx, yi = y0 + dy;
            const bool valid = (xi >= 0) & (xi < Ww) & (yi >= 0) & (yi < Hh);
            cidx[c] = valid ? (uint32_t)(base + yi * Ww + xi) * 512u : 0u;   // BYTE offset
            cwt[c]  = valid ? (dx ? fx : 1.f - fx) * (dy ? fy : 1.f - fy) : 0.f;
        }
    } else if (tid < 136) {
        const int h2 = tid - 128;
        const __bf16* ap = oa + (size_t)row * 384 + 256 + h2 * 16;
        float e[16], mx = -1e30f;
        #pragma unroll
        for (int i = 0; i < 16; ++i) { e[i] = (float)ap[i]; mx = fmaxf(mx, e[i]); }
        float s = 0.f;
        #pragma unroll
        for (int i = 0; i < 16; ++i) { e[i] = __expf(e[i] - mx); s += e[i]; }
        const float inv = 1.f / s;
        #pragma unroll
        for (int i = 0; i < 16; ++i) sw[h2][i] = e[i] * inv;
    }
    __syncthreads();
    if (tid < 128) {
        const float a = sw[h][lp];
        u32x4 pk0 = { cidx[0], __float_as_uint(cwt[0] * a), cidx[1], __float_as_uint(cwt[1] * a) };
        u32x4 pk1 = { cidx[2], __float_as_uint(cwt[2] * a), cidx[3], __float_as_uint(cwt[3] * a) };
        *(u32x4*)&sc[h][lp][0] = pk0;
        *(u32x4*)&sc[h][lp][4] = pk1;
    }
    __syncthreads();

    const char* __restrict__ vb = (const char*)value;
    const int gh  = tid >> 5;
    const uint32_t colb = (uint32_t)tid * 2u;   // byte offset of this channel
    float acc = 0.f;
    #pragma unroll
    for (int q = 0; q < 16; ++q) {
        const u32x4 a = *(const u32x4*)&sc[gh][q][0];
        const u32x4 b = *(const u32x4*)&sc[gh][q][4];
        acc += __uint_as_float(a.y) * __uint_as_float((uint32_t)(*(const uint16_t*)(vb + (size_t)(a.x + colb))) << 16);
        acc += __uint_as_float(a.w) * __uint_as_float((uint32_t)(*(const uint16_t*)(vb + (size_t)(a.z + colb))) << 16);
        acc += __uint_as_float(b.y) * __uint_as_float((uint32_t)(*(const uint16_t*)(vb + (size_t)(b.x + colb))) << 16);
        acc += __uint_as_float(b.w) * __uint_as_float((uint32_t)(*(const uint16_t*)(vb + (size_t)(b.z + colb))) << 16);
    }
    out[(size_t)row * 256 + tid] = (__bf16)acc;
}

// ---------------- launch ----------------
extern "C" void kernel_launch(void* const* d_in, const int* in_sizes, int n_in,
                              void* d_out, int out_size, void* d_ws, size_t ws_size,
                              hipStream_t stream)
{
    const float* src     = (const float*)d_in[0];
    const float* pos     = (const float*)d_in[1];
    const float* refp    = (const float*)d_in[2];
    const float* W_value = (const float*)d_in[5];
    const float* b_value = (const float*)d_in[6];
    const float* W_off   = (const float*)d_in[7];
    const float* b_off   = (const float*)d_in[8];
    const float* W_attn  = (const float*)d_in[9];
    const float* b_attn  = (const float*)d_in[10];
    const float* W_out   = (const float*)d_in[11];
    const float* b_out   = (const float*)d_in[12];
    const float* W1      = (const float*)d_in[13];
    const float* b1      = (const float*)d_in[14];
    const float* W2      = (const float*)d_in[15];
    const float* b2      = (const float*)d_in[16];
    const float* g1      = (const float*)d_in[17];
    const float* be1     = (const float*)d_in[18];
    const float* g2      = (const float*)d_in[19];
    const float* be2     = (const float*)d_in[20];
    float* outp = (float*)d_out;

    const int M = M_TOK;
    char* ws = (char*)d_ws;
    const size_t R2 = (size_t)M_PAD * 512;   // bytes of one [Mpad,256] bf16 buffer

    __bf16* src_b = (__bf16*)(ws);                    // [0, R2)
    __bf16* q_b   = (__bf16*)(ws + R2);               // [R2, 2R2)
    __bf16* val_b = (__bf16*)(ws + 2 * R2);           // [2R2, 3R2)
    __bf16* oa    = (__bf16*)(ws + 3 * R2);           // [3R2, 4.5R2)
    __bf16* samp  = (__bf16*)(ws + 9 * R2 / 2);       // [4.5R2, 5.5R2)
    __bf16* x_b   = (__bf16*)(ws + 11 * R2 / 2);      // [5.5R2, 6.5R2)
    __bf16* hbuf  = (__bf16*)(ws);                    // [0, 4R2) overlay (dead by FFN1)
    __bf16* wbase = (__bf16*)(ws + 13 * R2 / 2);
    __bf16* Wt_value = wbase;                          // [256][256]
    __bf16* Wt_oa    = wbase + 65536;                  // [384][256]
    __bf16* Wt_out   = wbase + 163840;                 // [256][256]
    __bf16* Wt1      = wbase + 229376;                 // [1024][256]
    __bf16* Wt2      = wbase + 491520;                 // [256][1024]
    float*  bias_oa  = (float*)(wbase + 753664);       // [384]

    const dim3 blk(256);
    const int n4 = M * 256 / 4;

    prep<<<dim3(737 + (n4 + 255) / 256), blk, 0, stream>>>(
        W_value, W_off, W_attn, W_out, W1, W2,
        Wt_value, Wt_oa, Wt_oa + 65536, Wt_out, Wt1, Wt2,
        b_off, b_attn, bias_oa,
        (const float4*)src, (const float4*)pos, (bf16x4*)src_b, (bf16x4*)q_b, n4);

    // value (416x4 tiles) + oa (416x6 tiles), 4160 wave-tiles -> 1040 blocks
    gemm_front_rd<<<dim3(1040), blk, 0, stream>>>(
        src_b, Wt_value, b_value, val_b,
        q_b,   Wt_oa,    bias_oa, oa, M);

    msda_sample<<<dim3(M), blk, 0, stream>>>(val_b, oa, refp, samp);

    // x_b = LN(src + samp @ W_out + b_out)  (bf16)
    gemm_ln_rd<__bf16, 256><<<dim3(M_PAD / 64), blk, 0, stream>>>(
        samp, Wt_out, b_out, src_b, g1, be1, x_b, M);

    // hbuf = relu(x_b @ W1 + b1)  : 416x16 tiles -> 1664 blocks
    gemm_ffn1_rd<<<dim3(1664), blk, 0, stream>>>(x_b, Wt1, b1, hbuf, M);

    // out = LN(x + hbuf @ W2 + b2)  (fp32, to d_out)
    gemm_ln_rd<float, 1024><<<dim3(M_PAD / 64), blk, 0, stream>>>(
        hbuf, Wt2, b2, x_b, g2, be2, outp, M);
}

// Round 7
// 305.723 us; speedup vs baseline: 1.3842x; 1.3842x over previous
//
#include <hip/hip_runtime.h>
#include <hip/hip_bf16.h>
#include <cstdint>

// ---------------- static problem config ----------------
#define D_MODEL   256
#define N_HEADS   8
#define N_LEVELS  4
#define N_POINTS  4
#define D_FFN     1024
#define D_HEAD    32
#define LEN_IN    13294          // 100*100 + 50*50 + 25*25 + 13*13
#define NBATCH    2
#define M_TOK     (NBATCH * LEN_IN)   // 26588
#define M_PAD     26624               // 208*128 = 416*64 = 832*32

__constant__ int c_lvl_h[4] = {100, 50, 25, 13};
__constant__ int c_lvl_w[4] = {100, 50, 25, 13};
__constant__ int c_lvl_s[4] = {0, 10000, 12500, 13125};

typedef __attribute__((ext_vector_type(8))) __bf16 bf16x8;
typedef __attribute__((ext_vector_type(4))) __bf16 bf16x4;
typedef __attribute__((ext_vector_type(4))) float  f32x4;
typedef __attribute__((ext_vector_type(4))) uint32_t u32x4;

__device__ __forceinline__ float bflo(uint32_t w) { return __uint_as_float(w << 16); }
__device__ __forceinline__ float bfhi(uint32_t w) { return __uint_as_float(w & 0xffff0000u); }

// async global->LDS, 16B per lane; lds base wave-uniform (lane i lands at base + i*16)
__device__ __forceinline__ void lds_direct16(const void* g, void* l) {
    __builtin_amdgcn_global_load_lds(
        (const __attribute__((address_space(1))) uint32_t*)(uintptr_t)g,
        (__attribute__((address_space(3))) uint32_t*)(uintptr_t)l,
        16, 0, 0);
}

// ---------------- prep: weight transposes + bias concat + src/q cvt, ONE dispatch ----------------
__global__ __launch_bounds__(256) void prep(
    const float* __restrict__ s0, const float* __restrict__ s1, const float* __restrict__ s2,
    const float* __restrict__ s3, const float* __restrict__ s4, const float* __restrict__ s5,
    __bf16* __restrict__ d0, __bf16* __restrict__ d1, __bf16* __restrict__ d2,
    __bf16* __restrict__ d3, __bf16* __restrict__ d4, __bf16* __restrict__ d5,
    const float* __restrict__ b_off, const float* __restrict__ b_attn,
    float* __restrict__ bias_oa,
    const float4* __restrict__ src, const float4* __restrict__ pos,
    bf16x4* __restrict__ sb, bf16x4* __restrict__ qb, int n4)
{
    const int tid = threadIdx.x;
    const int b = blockIdx.x;
    if (b >= 737) {   // cvt path
        const int i = (b - 737) * 256 + tid;
        if (i >= n4) return;
        const float4 s = src[i];
        const float4 p = pos[i];
        bf16x4 sv = { (__bf16)s.x, (__bf16)s.y, (__bf16)s.z, (__bf16)s.w };
        bf16x4 qv = { (__bf16)(s.x + p.x), (__bf16)(s.y + p.y),
                      (__bf16)(s.z + p.z), (__bf16)(s.w + p.w) };
        sb[i] = sv;
        qb[i] = qv;
        return;
    }
    if (b == 736) {   // bias concat: [b_off(256) | b_attn(128)]
        if (tid < 256) bias_oa[tid] = b_off[tid];
        if (tid < 128) bias_oa[256 + tid] = b_attn[tid];
        return;
    }
    const int tx = tid & 31;
    const int ty = tid >> 5;
    const int starts[7] = {0, 64, 128, 160, 224, 480, 736};
    const int Ks[6] = {256, 256, 256, 256, 256, 1024};
    const int Ns[6] = {256, 256, 128, 256, 1024, 256};
    const float* srcs[6] = {s0, s1, s2, s3, s4, s5};
    __bf16* dsts[6] = {d0, d1, d2, d3, d4, d5};
    int i = 0;
    while (b >= starts[i + 1]) ++i;
    const int t = b - starts[i];
    const int K = Ks[i], N = Ns[i];
    const float* W = srcs[i];
    __bf16* Wt = dsts[i];
    const int ntx = N >> 5;
    const int n0 = (t % ntx) * 32;
    const int k0 = (t / ntx) * 32;

    __shared__ float tl[32][33];
    #pragma unroll
    for (int j = 0; j < 4; ++j)
        tl[ty + j * 8][tx] = W[(size_t)(k0 + ty + j * 8) * N + n0 + tx];
    __syncthreads();
    #pragma unroll
    for (int j = 0; j < 4; ++j)
        Wt[(size_t)(n0 + ty + j * 8) * K + k0 + tx] = (__bf16)tl[tx][ty + j * 8];
}

// ---------------- bf16 MFMA GEMM core (m97 structure, 128x128 tile, NP=2) ----------------
// C[M,N] = act(A @ Bt^T + bias), bf16 output. Coalesced LDS-assembled epilogue.
template <bool RELU, int K>
__device__ __forceinline__ void gemm_core(
    const __bf16* __restrict__ A, const __bf16* __restrict__ Bt,
    const float* __restrict__ bias, __bf16* __restrict__ C,
    int M, int N, int bm, int bn)
{
    // staging: As 2*128*32 (8K elems) + Bs 2*128*32 (8K elems) = 16K elems
    // epilogue: C-tile 128 x 136 = 17408 elems (overlays both)
    __shared__ __bf16 smem[17408];
    __bf16* As = smem;
    __bf16* Bs = smem + 8192;

    const int tid  = threadIdx.x;
    const int lane = tid & 63;
    const int wv   = tid >> 6;
    const int wm   = (wv >> 1) * 64;
    const int wn   = (wv & 1) * 64;
    const int srow = lane >> 2;
    const int skc  = (lane & 3) * 8;
    const int fm   = lane & 15;
    const int fko  = (lane >> 4) * 8;

    f32x4 acc[4][4] = {};

    for (int k0 = 0; k0 < K; k0 += 64) {
        #pragma unroll
        for (int p = 0; p < 2; ++p) {
            #pragma unroll
            for (int c = 0; c < 2; ++c) {
                const int r = wv * 32 + c * 16;
                lds_direct16(A  + (size_t)(bm + r + srow) * K + k0 + p * 32 + skc, As + p * 4096 + r * 32);
                lds_direct16(Bt + (size_t)(bn + r + srow) * K + k0 + p * 32 + skc, Bs + p * 4096 + r * 32);
            }
        }
        __syncthreads();

        #pragma unroll
        for (int p = 0; p < 2; ++p) {
            bf16x8 af[4], bfr[4];
            #pragma unroll
            for (int t = 0; t < 4; ++t) {
                af[t]  = *(const bf16x8*)(As + p * 4096 + (wm + t * 16 + fm) * 32 + fko);
                bfr[t] = *(const bf16x8*)(Bs + p * 4096 + (wn + t * 16 + fm) * 32 + fko);
            }
            #pragma unroll
            for (int mt = 0; mt < 4; ++mt)
                #pragma unroll
                for (int nt = 0; nt < 4; ++nt)
                    acc[mt][nt] = __builtin_amdgcn_mfma_f32_16x16x32_bf16(
                        af[mt], bfr[nt], acc[mt][nt], 0, 0, 0);
        }
        __syncthreads();
    }

    // epilogue: C/D layout col=lane&15, row=(lane>>4)*4+reg [m89-verified]
    // assemble bf16 tile in LDS (stride 136), then coalesced bf16x8 stores.
    const int ecol = lane & 15;
    const int erow = (lane >> 4) * 4;
    #pragma unroll
    for (int nt = 0; nt < 4; ++nt) {
        const int cl = wn + nt * 16 + ecol;
        const float bv = bias[bn + cl];
        #pragma unroll
        for (int mt = 0; mt < 4; ++mt) {
            #pragma unroll
            for (int r = 0; r < 4; ++r) {
                const int rl = wm + mt * 16 + erow + r;
                float v = acc[mt][nt][r] + bv;
                if (RELU) v = fmaxf(v, 0.f);
                smem[rl * 136 + cl] = (__bf16)v;
            }
        }
    }
    __syncthreads();
    #pragma unroll
    for (int rr = 0; rr < 8; ++rr) {
        const int idx = rr * 256 + tid;
        const int row = idx >> 4;
        const int ch  = idx & 15;
        if (bm + row < M)
            *(bf16x8*)(C + (size_t)(bm + row) * N + bn + ch * 8) =
                *(const bf16x8*)(smem + row * 136 + ch * 8);
    }
}

// front GEMM: blocks x<2 -> value (src_b @ Wt_value), x>=2 -> oa (q_b @ Wt_oa)
__global__ __launch_bounds__(256) void gemm_front(
    const __bf16* __restrict__ A0, const __bf16* __restrict__ B0,
    const float* __restrict__ bi0, __bf16* __restrict__ C0,
    const __bf16* __restrict__ A1, const __bf16* __restrict__ B1,
    const float* __restrict__ bi1, __bf16* __restrict__ C1, int M)
{
    const int bx = blockIdx.x;
    if (bx < 2)
        gemm_core<false, 256>(A0, B0, bi0, C0, M, 256, blockIdx.y * 128, bx * 128);
    else
        gemm_core<false, 256>(A1, B1, bi1, C1, M, 384, blockIdx.y * 128, (bx - 2) * 128);
}

// FFN1: relu(x_b @ W1 + b1), N=1024
__global__ __launch_bounds__(256) void gemm_ffn1(
    const __bf16* __restrict__ A, const __bf16* __restrict__ Bt,
    const float* __restrict__ bias, __bf16* __restrict__ C, int M)
{
    gemm_core<true, 256>(A, Bt, bias, C, M, 1024, blockIdx.y * 128, blockIdx.x * 128);
}

// ---------------- GEMM + residual + LayerNorm fused (32x256 tile, 4 waves) ----------------
// C_ln = LN((A @ Bt^T + bias) + res) * gamma + beta. Wave wv owns cols [wv*64, wv*64+64).
template <typename OutT, int K>
__global__ __launch_bounds__(256) void gemm_ln32(
    const __bf16* __restrict__ A, const __bf16* __restrict__ Bt,
    const float* __restrict__ bias, const __bf16* __restrict__ res,
    const float* __restrict__ gamma, const float* __restrict__ beta,
    OutT* __restrict__ Cout, int M)
{
    // staging: As 2*32*32 = 2048 elems (4KB), Bs 2*256*32 = 16384 elems (32KB)
    // epilogue: bf16 tile 32x264 = 8448 elems, or fp32 tile 32x260 = 33280 B (fits 36KB)
    __shared__ __bf16 smem[18432];
    __bf16* As = smem;
    __bf16* Bs = smem + 2048;
    __shared__ float lnsum[32][4];
    __shared__ float lnsq[32][4];
    __shared__ float lnstat[32][2];

    const int tid  = threadIdx.x;
    const int lane = tid & 63;
    const int wv   = tid >> 6;
    const int bm   = blockIdx.x * 32;
    const int wn   = wv * 64;
    const int srow = lane >> 2;
    const int skc  = (lane & 3) * 8;
    const int fm   = lane & 15;
    const int fko  = (lane >> 4) * 8;

    f32x4 acc[2][4] = {};

    for (int k0 = 0; k0 < K; k0 += 64) {
        // A staging: one 16B chunk per thread (2 panels x 32 rows)
        {
            const int p  = wv >> 1;
            const int rh = (wv & 1) * 16;
            lds_direct16(A + (size_t)(bm + rh + srow) * K + k0 + p * 32 + skc,
                         As + p * 1024 + rh * 32);
        }
        // B staging: full 256 rows, both panels
        #pragma unroll
        for (int p = 0; p < 2; ++p) {
            #pragma unroll
            for (int c = 0; c < 4; ++c) {
                const int r = wv * 64 + c * 16;
                lds_direct16(Bt + (size_t)(r + srow) * K + k0 + p * 32 + skc,
                             Bs + p * 8192 + r * 32);
            }
        }
        __syncthreads();

        #pragma unroll
        for (int p = 0; p < 2; ++p) {
            bf16x8 af[2], bfr[4];
            #pragma unroll
            for (int mt = 0; mt < 2; ++mt)
                af[mt] = *(const bf16x8*)(As + p * 1024 + (mt * 16 + fm) * 32 + fko);
            #pragma unroll
            for (int nt = 0; nt < 4; ++nt)
                bfr[nt] = *(const bf16x8*)(Bs + p * 8192 + (wn + nt * 16 + fm) * 32 + fko);
            #pragma unroll
            for (int mt = 0; mt < 2; ++mt)
                #pragma unroll
                for (int nt = 0; nt < 4; ++nt)
                    acc[mt][nt] = __builtin_amdgcn_mfma_f32_16x16x32_bf16(
                        af[mt], bfr[nt], acc[mt][nt], 0, 0, 0);
        }
        __syncthreads();
    }

    const int ecol = lane & 15;
    const int erow = (lane >> 4) * 4;

    // bias + residual
    float g4[4], b4[4];
    #pragma unroll
    for (int nt = 0; nt < 4; ++nt) {
        const int col = wn + nt * 16 + ecol;
        g4[nt] = gamma[col];
        b4[nt] = beta[col];
        const float bv = bias[col];
        #pragma unroll
        for (int mt = 0; mt < 2; ++mt) {
            #pragma unroll
            for (int r = 0; r < 4; ++r) {
                const int row = bm + mt * 16 + erow + r;
                acc[mt][nt][r] += bv + (float)res[(size_t)row * 256 + col];
            }
        }
    }

    // per-row sums
    #pragma unroll
    for (int mt = 0; mt < 2; ++mt) {
        #pragma unroll
        for (int r = 0; r < 4; ++r) {
            float s  = acc[mt][0][r] + acc[mt][1][r] + acc[mt][2][r] + acc[mt][3][r];
            float s2 = acc[mt][0][r] * acc[mt][0][r] + acc[mt][1][r] * acc[mt][1][r]
                     + acc[mt][2][r] * acc[mt][2][r] + acc[mt][3][r] * acc[mt][3][r];
            #pragma unroll
            for (int o = 1; o < 16; o <<= 1) {
                s  += __shfl_xor(s, o);
                s2 += __shfl_xor(s2, o);
            }
            if (ecol == 0) {
                const int rl = mt * 16 + erow + r;
                lnsum[rl][wv] = s;
                lnsq[rl][wv]  = s2;
            }
        }
    }
    __syncthreads();
    if (tid < 32) {
        const float s  = lnsum[tid][0] + lnsum[tid][1] + lnsum[tid][2] + lnsum[tid][3];
        const float s2 = lnsq[tid][0] + lnsq[tid][1] + lnsq[tid][2] + lnsq[tid][3];
        const float mu = s * (1.f / 256.f);
        const float var = s2 * (1.f / 256.f) - mu * mu;
        lnstat[tid][0] = mu;
        lnstat[tid][1] = rsqrtf(var + 1e-5f);
    }
    __syncthreads();

    // normalize into LDS tile, then coalesced stores
    if constexpr (sizeof(OutT) == 2) {
        __bf16* ct = smem;   // [32][264]
        #pragma unroll
        for (int mt = 0; mt < 2; ++mt) {
            #pragma unroll
            for (int r = 0; r < 4; ++r) {
                const int rl = mt * 16 + erow + r;
                const float mu = lnstat[rl][0];
                const float rs = lnstat[rl][1];
                #pragma unroll
                for (int nt = 0; nt < 4; ++nt) {
                    const int col = wn + nt * 16 + ecol;
                    ct[rl * 264 + col] = (__bf16)((acc[mt][nt][r] - mu) * rs * g4[nt] + b4[nt]);
                }
            }
        }
        __syncthreads();
        #pragma unroll
        for (int rr = 0; rr < 4; ++rr) {
            const int idx = rr * 256 + tid;
            const int row = idx >> 5;
            const int ch  = idx & 31;
            if (bm + row < M)
                *(bf16x8*)((__bf16*)Cout + (size_t)(bm + row) * 256 + ch * 8) =
                    *(const bf16x8*)(ct + row * 264 + ch * 8);
        }
    } else {
        float* ct = (float*)smem;   // [32][260]
        #pragma unroll
        for (int mt = 0; mt < 2; ++mt) {
            #pragma unroll
            for (int r = 0; r < 4; ++r) {
                const int rl = mt * 16 + erow + r;
                const float mu = lnstat[rl][0];
                const float rs = lnstat[rl][1];
                #pragma unroll
                for (int nt = 0; nt < 4; ++nt) {
                    const int col = wn + nt * 16 + ecol;
                    ct[rl * 260 + col] = (acc[mt][nt][r] - mu) * rs * g4[nt] + b4[nt];
                }
            }
        }
        __syncthreads();
        #pragma unroll
        for (int rr = 0; rr < 8; ++rr) {
            const int idx = rr * 256 + tid;
            const int row = idx >> 6;
            const int ch  = idx & 63;
            if (bm + row < M) {
                float4 v = *(const float4*)(ct + row * 260 + ch * 4);
                *(float4*)((float*)Cout + (size_t)(bm + row) * 256 + ch * 4) = v;
            }
        }
    }
}

// ---------------- deformable sampling ----------------
// One token per block, 256 thr = 8 heads x 32 channels. Corner idx pre-scaled to BYTES.
__global__ __launch_bounds__(256) void msda_sample(
    const __bf16* __restrict__ value, // [Mpad, 256] bf16
    const __bf16* __restrict__ oa,    // [Mpad, 384] bf16: [off(256) | attn(128)]
    const float* __restrict__ refp,   // [M, 4, 2]
    __bf16* __restrict__ out)         // [Mpad, 256] bf16
{
    __shared__ uint32_t sc[8][16][8]; // per (h,lp): {i0,w0,i1,w1,i2,w2,i3,w3} ; 4 KB
    __shared__ float sw[8][16];       // softmax weights

    const int row = blockIdx.x;
    const int tid = threadIdx.x;

    uint32_t cidx[4];
    float    cwt[4];
    const int h  = tid >> 4;
    const int lp = tid & 15;

    if (tid < 128) {
        const int l  = lp >> 2;
        const int Ww = c_lvl_w[l];
        const int Hh = c_lvl_h[l];
        const uint32_t opk = *(const uint32_t*)(oa + (size_t)row * 384 + h * 32 + lp * 2);
        const float ox = bflo(opk), oy = bfhi(opk);
        const float rx = refp[((size_t)row * 4 + l) * 2 + 0];
        const float ry = refp[((size_t)row * 4 + l) * 2 + 1];
        const float x = (rx + ox / (float)Ww) * (float)Ww - 0.5f;
        const float y = (ry + oy / (float)Hh) * (float)Hh - 0.5f;
        const float xf = floorf(x), yf = floorf(y);
        const float fx = x - xf,    fy = y - yf;
        const int x0 = (int)xf, y0 = (int)yf;
        const int n  = row / LEN_IN;
        const int base = n * LEN_IN + c_lvl_s[l];
        #pragma unroll
        for (int c = 0; c < 4; ++c) {
            const int dx = c & 1, dy = c >> 1;
            const int xi = x0 + dx, yi = y0 + dy;
            const bool valid = (xi >= 0) & (xi < Ww) & (yi >= 0) & (yi < Hh);
            cidx[c] = valid ? (uint32_t)(base + yi * Ww + xi) * 512u : 0u;   // BYTE offset
            cwt[c]  = valid ? (dx ? fx : 1.f - fx) * (dy ? fy : 1.f - fy) : 0.f;
        }
    } else if (tid < 136) {
        const int h2 = tid - 128;
        const __bf16* ap = oa + (size_t)row * 384 + 256 + h2 * 16;
        float e[16], mx = -1e30f;
        #pragma unroll
        for (int i = 0; i < 16; ++i) { e[i] = (float)ap[i]; mx = fmaxf(mx, e[i]); }
        float s = 0.f;
        #pragma unroll
        for (int i = 0; i < 16; ++i) { e[i] = __expf(e[i] - mx); s += e[i]; }
        const float inv = 1.f / s;
        #pragma unroll
        for (int i = 0; i < 16; ++i) sw[h2][i] = e[i] * inv;
    }
    __syncthreads();
    if (tid < 128) {
        const float a = sw[h][lp];
        u32x4 pk0 = { cidx[0], __float_as_uint(cwt[0] * a), cidx[1], __float_as_uint(cwt[1] * a) };
        u32x4 pk1 = { cidx[2], __float_as_uint(cwt[2] * a), cidx[3], __float_as_uint(cwt[3] * a) };
        *(u32x4*)&sc[h][lp][0] = pk0;
        *(u32x4*)&sc[h][lp][4] = pk1;
    }
    __syncthreads();

    const char* __restrict__ vb = (const char*)value;
    const int gh  = tid >> 5;
    const uint32_t colb = (uint32_t)tid * 2u;   // byte offset of this channel
    float acc = 0.f;
    #pragma unroll
    for (int q = 0; q < 16; ++q) {
        const u32x4 a = *(const u32x4*)&sc[gh][q][0];
        const u32x4 b = *(const u32x4*)&sc[gh][q][4];
        acc += __uint_as_float(a.y) * __uint_as_float((uint32_t)(*(const uint16_t*)(vb + (size_t)(a.x + colb))) << 16);
        acc += __uint_as_float(a.w) * __uint_as_float((uint32_t)(*(const uint16_t*)(vb + (size_t)(a.z + colb))) << 16);
        acc += __uint_as_float(b.y) * __uint_as_float((uint32_t)(*(const uint16_t*)(vb + (size_t)(b.x + colb))) << 16);
        acc += __uint_as_float(b.w) * __uint_as_float((uint32_t)(*(const uint16_t*)(vb + (size_t)(b.z + colb))) << 16);
    }
    out[(size_t)row * 256 + tid] = (__bf16)acc;
}

// ---------------- launch ----------------
extern "C" void kernel_launch(void* const* d_in, const int* in_sizes, int n_in,
                              void* d_out, int out_size, void* d_ws, size_t ws_size,
                              hipStream_t stream)
{
    const float* src     = (const float*)d_in[0];
    const float* pos     = (const float*)d_in[1];
    const float* refp    = (const float*)d_in[2];
    const float* W_value = (const float*)d_in[5];
    const float* b_value = (const float*)d_in[6];
    const float* W_off   = (const float*)d_in[7];
    const float* b_off   = (const float*)d_in[8];
    const float* W_attn  = (const float*)d_in[9];
    const float* b_attn  = (const float*)d_in[10];
    const float* W_out   = (const float*)d_in[11];
    const float* b_out   = (const float*)d_in[12];
    const float* W1      = (const float*)d_in[13];
    const float* b1      = (const float*)d_in[14];
    const float* W2      = (const float*)d_in[15];
    const float* b2      = (const float*)d_in[16];
    const float* g1      = (const float*)d_in[17];
    const float* be1     = (const float*)d_in[18];
    const float* g2      = (const float*)d_in[19];
    const float* be2     = (const float*)d_in[20];
    float* outp = (float*)d_out;

    const int M = M_TOK;
    char* ws = (char*)d_ws;
    const size_t R2 = (size_t)M_PAD * 512;   // bytes of one [Mpad,256] bf16 buffer

    __bf16* src_b = (__bf16*)(ws);                    // [0, R2)
    __bf16* q_b   = (__bf16*)(ws + R2);               // [R2, 2R2)
    __bf16* val_b = (__bf16*)(ws + 2 * R2);           // [2R2, 3R2)
    __bf16* oa    = (__bf16*)(ws + 3 * R2);           // [3R2, 4.5R2)
    __bf16* samp  = (__bf16*)(ws + 9 * R2 / 2);       // [4.5R2, 5.5R2)
    __bf16* x_b   = (__bf16*)(ws + 11 * R2 / 2);      // [5.5R2, 6.5R2)
    __bf16* hbuf  = (__bf16*)(ws);                    // [0, 4R2) overlay (dead by FFN1)
    __bf16* wbase = (__bf16*)(ws + 13 * R2 / 2);
    __bf16* Wt_value = wbase;                          // [256][256]
    __bf16* Wt_oa    = wbase + 65536;                  // [384][256]
    __bf16* Wt_out   = wbase + 163840;                 // [256][256]
    __bf16* Wt1      = wbase + 229376;                 // [1024][256]
    __bf16* Wt2      = wbase + 491520;                 // [256][1024]
    float*  bias_oa  = (float*)(wbase + 753664);       // [384]

    const dim3 blk(256);
    const int n4 = M * 256 / 4;
    const int gm = M_PAD / 128;  // 208

    prep<<<dim3(737 + (n4 + 255) / 256), blk, 0, stream>>>(
        W_value, W_off, W_attn, W_out, W1, W2,
        Wt_value, Wt_oa, Wt_oa + 65536, Wt_out, Wt1, Wt2,
        b_off, b_attn, bias_oa,
        (const float4*)src, (const float4*)pos, (bf16x4*)src_b, (bf16x4*)q_b, n4);

    // value (2 n-tiles) + oa (3 n-tiles): 5 x 208 = 1040 blocks
    gemm_front<<<dim3(5, gm), blk, 0, stream>>>(
        src_b, Wt_value, b_value, val_b,
        q_b,   Wt_oa,    bias_oa, oa, M);

    msda_sample<<<dim3(M), blk, 0, stream>>>(val_b, oa, refp, samp);

    // x_b = LN(src + samp @ W_out + b_out)  (bf16), 32-row blocks
    gemm_ln32<__bf16, 256><<<dim3(M_PAD / 32), blk, 0, stream>>>(
        samp, Wt_out, b_out, src_b, g1, be1, x_b, M);

    // hbuf = relu(x_b @ W1 + b1)
    gemm_ffn1<<<dim3(8, gm), blk, 0, stream>>>(x_b, Wt1, b1, hbuf, M);

    // out = LN(x_b + hbuf @ W2 + b2)  (fp32, to d_out), 32-row blocks
    gemm_ln32<float, 1024><<<dim3(M_PAD / 32), blk, 0, stream>>>(
        hbuf, Wt2, b2, x_b, g2, be2, outp, M);
}